// Round 8
// baseline (518.743 us; speedup 1.0000x reference)
//
#include <hip/hip_runtime.h>
#include <cstdint>
#include <cstddef>

typedef __attribute__((ext_vector_type(8))) short short8;
typedef __attribute__((ext_vector_type(4))) float f4;
typedef __attribute__((ext_vector_type(4))) unsigned int u4;

static __device__ __forceinline__ unsigned short f2bf(float x) {
  unsigned int u = __float_as_uint(x);
  unsigned int r = (u + 0x7FFFu + ((u >> 16) & 1u)) >> 16;  // RNE
  return (unsigned short)r;
}

// ---------------- transpose fp32 src -> bf16 dst: dst[n][k] = src[k][n] ----------------
__global__ __launch_bounds__(256) void k_transpose_f(
    const float* __restrict__ src, unsigned short* __restrict__ dst, int R, int C) {
  __shared__ alignas(16) unsigned short tile[64 * 72];
  int tid = threadIdx.x;
  int c0 = blockIdx.x * 64, r0 = blockIdx.y * 64;
#pragma unroll
  for (int s = 0; s < 2; ++s) {
    int chunk = tid + s * 256;
    int c8 = chunk & 7, r = chunk >> 3;
    const float* p = src + (size_t)(r0 + r) * C + c0 + c8 * 8;
    f4 a = *(const f4*)p;
    f4 b = *(const f4*)(p + 4);
    union { unsigned short u[8]; u4 v; } pk;
#pragma unroll
    for (int i = 0; i < 4; ++i) { pk.u[i] = f2bf(a[i]); pk.u[4 + i] = f2bf(b[i]); }
    *(u4*)(tile + r * 72 + c8 * 8) = pk.v;
  }
  __syncthreads();
#pragma unroll
  for (int s = 0; s < 2; ++s) {
    int chunk = tid + s * 256;
    int r8 = chunk & 7, c = chunk >> 3;
    union { unsigned short u[8]; u4 v; } pk;
#pragma unroll
    for (int i = 0; i < 8; ++i) pk.u[i] = tile[(r8 * 8 + i) * 72 + c];
    *(u4*)(dst + (size_t)(c0 + c) * R + r0 + r8 * 8) = pk.v;
  }
}

// ---------------- GEMM1: C_bf16[M,N] = A_f32[M,K] @ Bt_bf16[N,K]^T ----------------
__global__ __launch_bounds__(256) void k_gemm_f32A(
    const float* __restrict__ A, const unsigned short* __restrict__ Bt,
    unsigned short* __restrict__ C, int M, int N, int K) {
  __shared__ alignas(16) unsigned short As[128 * 72];
  __shared__ alignas(16) unsigned short Bs[128 * 72];
  int tid = threadIdx.x;
  int w = tid >> 6, lane = tid & 63, quad = lane >> 4, l16 = lane & 15;
  int wr = w >> 1, wc = w & 1;
  int bm = blockIdx.y * 128, bn = blockIdx.x * 128;
  f4 zero = {0.f, 0.f, 0.f, 0.f};
  f4 acc[4][4];
#pragma unroll
  for (int i = 0; i < 4; ++i)
#pragma unroll
    for (int j = 0; j < 4; ++j) acc[i][j] = zero;

  for (int k0 = 0; k0 < K; k0 += 64) {
    __syncthreads();
#pragma unroll
    for (int s = 0; s < 4; ++s) {
      int chunk = tid + s * 256;
      int c8 = chunk & 7, r = chunk >> 3;
      const float* p = A + (size_t)(bm + r) * K + k0 + c8 * 8;
      f4 a0 = *(const f4*)p;
      f4 a1 = *(const f4*)(p + 4);
      union { unsigned short u[8]; u4 v; } pk;
#pragma unroll
      for (int i = 0; i < 4; ++i) { pk.u[i] = f2bf(a0[i]); pk.u[4 + i] = f2bf(a1[i]); }
      *(u4*)(As + r * 72 + c8 * 8) = pk.v;
      *(u4*)(Bs + r * 72 + c8 * 8) =
          *(const u4*)(Bt + (size_t)(bn + r) * K + k0 + c8 * 8);
    }
    __syncthreads();
#pragma unroll
    for (int ks = 0; ks < 2; ++ks) {
      short8 af[4], bf[4];
#pragma unroll
      for (int i = 0; i < 4; ++i)
        af[i] = *(const short8*)(As + (wr * 64 + i * 16 + l16) * 72 + ks * 32 + quad * 8);
#pragma unroll
      for (int j = 0; j < 4; ++j)
        bf[j] = *(const short8*)(Bs + (wc * 64 + j * 16 + l16) * 72 + ks * 32 + quad * 8);
#pragma unroll
      for (int i = 0; i < 4; ++i)
#pragma unroll
        for (int j = 0; j < 4; ++j)
          acc[i][j] = __builtin_amdgcn_mfma_f32_16x16x32_bf16(af[i], bf[j], acc[i][j], 0, 0, 0);
    }
  }
#pragma unroll
  for (int i = 0; i < 4; ++i) {
    int row = bm + wr * 64 + i * 16 + quad * 4;
#pragma unroll
    for (int j = 0; j < 4; ++j) {
      int col = bn + wc * 64 + j * 16 + l16;
#pragma unroll
      for (int r = 0; r < 4; ++r)
        C[(size_t)(row + r) * N + col] = f2bf(acc[i][j][r]);
    }
  }
}

// ---------------- GEMM2: C_f32[M,N] = A_bf16[M,K] @ Bt_bf16[N,K]^T ----------------
__global__ __launch_bounds__(256) void k_gemm_f32C(
    const unsigned short* __restrict__ A, const unsigned short* __restrict__ Bt,
    float* __restrict__ C, int M, int N, int K) {
  __shared__ alignas(16) unsigned short As[128 * 72];
  __shared__ alignas(16) unsigned short Bs[128 * 72];
  int tid = threadIdx.x;
  int w = tid >> 6, lane = tid & 63, quad = lane >> 4, l16 = lane & 15;
  int wr = w >> 1, wc = w & 1;
  int bm = blockIdx.y * 128, bn = blockIdx.x * 128;
  f4 zero = {0.f, 0.f, 0.f, 0.f};
  f4 acc[4][4];
#pragma unroll
  for (int i = 0; i < 4; ++i)
#pragma unroll
    for (int j = 0; j < 4; ++j) acc[i][j] = zero;

  for (int k0 = 0; k0 < K; k0 += 64) {
    __syncthreads();
#pragma unroll
    for (int s = 0; s < 4; ++s) {
      int chunk = tid + s * 256;
      int c8 = chunk & 7, r = chunk >> 3;
      *(u4*)(As + r * 72 + c8 * 8) =
          *(const u4*)(A + (size_t)(bm + r) * K + k0 + c8 * 8);
      *(u4*)(Bs + r * 72 + c8 * 8) =
          *(const u4*)(Bt + (size_t)(bn + r) * K + k0 + c8 * 8);
    }
    __syncthreads();
#pragma unroll
    for (int ks = 0; ks < 2; ++ks) {
      short8 af[4], bf[4];
#pragma unroll
      for (int i = 0; i < 4; ++i)
        af[i] = *(const short8*)(As + (wr * 64 + i * 16 + l16) * 72 + ks * 32 + quad * 8);
#pragma unroll
      for (int j = 0; j < 4; ++j)
        bf[j] = *(const short8*)(Bs + (wc * 64 + j * 16 + l16) * 72 + ks * 32 + quad * 8);
#pragma unroll
      for (int i = 0; i < 4; ++i)
#pragma unroll
        for (int j = 0; j < 4; ++j)
          acc[i][j] = __builtin_amdgcn_mfma_f32_16x16x32_bf16(af[i], bf[j], acc[i][j], 0, 0, 0);
    }
  }
#pragma unroll
  for (int i = 0; i < 4; ++i) {
    int row = bm + wr * 64 + i * 16 + quad * 4;
#pragma unroll
    for (int j = 0; j < 4; ++j) {
      int col = bn + wc * 64 + j * 16 + l16;
#pragma unroll
      for (int r = 0; r < 4; ++r)
        C[(size_t)(row + r) * N + col] = acc[i][j][r];
    }
  }
}

// ---------------- RoPE in place on QKV (Q also scaled by 1/sqrt(D)) ----------------
__global__ __launch_bounds__(256) void k_rope(unsigned short* __restrict__ QKV) {
  int gid = blockIdx.x * 256 + threadIdx.x;
  const int TQ = 2 * 2048 * 16 * 64;
  bool isq = gid < TQ;
  int g = isq ? gid : gid - TQ;
  int d = g & 63; g >>= 6;
  int nh = isq ? 16 : 4;
  int h = g & (nh - 1); g >>= (isq ? 4 : 2);
  int t = g & 2047; int b = g >> 11;
  size_t p = (size_t)(b * 2048 + t) * 3072 + (isq ? 0 : 2048) + h * 128 + d;
  float x0 = __uint_as_float((unsigned int)QKV[p] << 16);
  float x1 = __uint_as_float((unsigned int)QKV[p + 64] << 16);
  float freq = exp2f(-(float)d * 0.20762050593046f);  // log2(10000)/64
  float ang = (float)t * freq;
  float cv = __cosf(ang), sv = __sinf(ang);
  float o0 = x0 * cv - x1 * sv;
  float o1 = x1 * cv + x0 * sv;
  if (isq) { o0 *= 0.088388347648318f; o1 *= 0.088388347648318f; }  // 1/sqrt(128)
  QKV[p] = f2bf(o0);
  QKV[p + 64] = f2bf(o1);
}

// ---------------- V transpose: VT[b,hk,d,t] = QKV[b*T+t, 2560+hk*128+d] ----------------
__global__ __launch_bounds__(256) void k_vtrans(
    const unsigned short* __restrict__ QKV, unsigned short* __restrict__ VT) {
  int gid = blockIdx.x * 256 + threadIdx.x;
  int t = gid & 2047; int g = gid >> 11;
  int d = g & 127; g >>= 7;
  int hk = g & 3; int b = g >> 2;
  VT[gid] = QKV[(size_t)(b * 2048 + t) * 3072 + 2560 + hk * 128 + d];
}

// ---------------- Flash attention (S^T formulation, GQA, causal, LDS-staged) ----------------
// Single 64-row q-tile per block, grid (32,32) = 1024 blocks = 4/CU (LDS-limited).
// Co-resident blocks are {L, L+256, L+512, L+768} (same x, y differing by 8), so
// q-tile index bx is derived from j=(y>>3)&3 via a per-slice bijection whose four
// co-resident costs sum to exactly 66 chunks -> per-CU work balanced by construction.
__global__ __launch_bounds__(256) void k_attn(
    const unsigned short* __restrict__ QKV,  // [B*T,3072], Q roped+scaled
    const unsigned short* __restrict__ VT,   // [B,4,128,T]
    unsigned short* __restrict__ Y) {        // [B*T,2048]
  __shared__ alignas(16) unsigned short Ks[64 * 136];   // 64 keys x 128 d
  __shared__ alignas(16) unsigned short Vs[128 * 72];   // 128 d x 64 keys
  int tid = threadIdx.x;
  int w = tid >> 6, lane = tid & 63, quad = lane >> 4, l16 = lane & 15;
  int bh = blockIdx.y; int b = bh >> 4, h = bh & 15, hk = h >> 2;
  int x = blockIdx.x, j = (bh >> 3) & 3;
  int bx = (j == 0) ? x
         : (j == 1) ? (31 - x)
         : (j == 2) ? ((x + 16) & 31)
                    : ((15 - x) & 31);
  int q0 = bx * 64 + w * 16;
  const unsigned short* Qh = QKV + (size_t)b * 2048 * 3072 + h * 128;
  const unsigned short* Kh = QKV + (size_t)b * 2048 * 3072 + 2048 + hk * 128;
  const unsigned short* Vh = VT + ((size_t)(b * 4 + hk) * 128) * 2048;

  short8 qf[4];
#pragma unroll
  for (int ks = 0; ks < 4; ++ks)
    qf[ks] = *(const short8*)(Qh + (size_t)(q0 + l16) * 3072 + ks * 32 + quad * 8);

  f4 zero = {0.f, 0.f, 0.f, 0.f};
  f4 o[8];
#pragma unroll
  for (int i = 0; i < 8; ++i) o[i] = zero;
  float m = -1e30f, l = 0.f;

  int nch = bx + 1;  // 64-key chunks, causal
  for (int kc = 0; kc < nch; ++kc) {
    int K0 = kc * 64;
    __syncthreads();  // prev iter's LDS reads done before overwrite
    // stage K tile: 64 rows x 128 shorts = 1024 u4 chunks (16 per row)
#pragma unroll
    for (int s = 0; s < 4; ++s) {
      int c = tid + s * 256;
      int r = c >> 4, c16 = c & 15;
      *(u4*)(Ks + r * 136 + c16 * 8) =
          *(const u4*)(Kh + (size_t)(K0 + r) * 3072 + c16 * 8);
    }
    // stage V^T tile: 128 rows x 64 shorts = 1024 u4 chunks (8 per row)
#pragma unroll
    for (int s = 0; s < 4; ++s) {
      int c = tid + s * 256;
      int r = c >> 3, c8 = c & 7;
      *(u4*)(Vs + r * 72 + c8 * 8) =
          *(const u4*)(Vh + (size_t)r * 2048 + K0 + c8 * 8);
    }
    __syncthreads();

    // S^T = K . Q^T : 4 key-subtiles of 16
    f4 st[4];
#pragma unroll
    for (int kt = 0; kt < 4; ++kt) {
      st[kt] = zero;
#pragma unroll
      for (int ks = 0; ks < 4; ++ks) {
        short8 kf = *(const short8*)(Ks + (kt * 16 + l16) * 136 + ks * 32 + quad * 8);
        st[kt] = __builtin_amdgcn_mfma_f32_16x16x32_bf16(kf, qf[ks], st[kt], 0, 0, 0);
      }
    }
    int q = q0 + l16;
    if (kc == nch - 1) {  // only the diagonal chunk needs masking
#pragma unroll
      for (int kt = 0; kt < 4; ++kt)
#pragma unroll
        for (int r = 0; r < 4; ++r)
          if (K0 + kt * 16 + quad * 4 + r > q) st[kt][r] = -1e30f;
    }
    float sm = -1e30f;
#pragma unroll
    for (int kt = 0; kt < 4; ++kt)
#pragma unroll
      for (int r = 0; r < 4; ++r) sm = fmaxf(sm, st[kt][r]);
    sm = fmaxf(sm, __shfl_xor(sm, 16));
    sm = fmaxf(sm, __shfl_xor(sm, 32));
    float mnew = fmaxf(m, sm);
    float alpha = __expf(m - mnew);
    f4 pv[4];
    float rs = 0.f;
#pragma unroll
    for (int kt = 0; kt < 4; ++kt)
#pragma unroll
      for (int r = 0; r < 4; ++r) {
        pv[kt][r] = __expf(st[kt][r] - mnew);
        rs += pv[kt][r];
      }
    rs += __shfl_xor(rs, 16);
    rs += __shfl_xor(rs, 32);
    l = l * alpha + rs;
    m = mnew;
#pragma unroll
    for (int i = 0; i < 8; ++i) o[i] *= alpha;

    // P (C-layout of S^T tiles) -> P^T B-fragments; PV accumulate.
#pragma unroll
    for (int kh = 0; kh < 2; ++kh) {
      short8 pb;
#pragma unroll
      for (int jj = 0; jj < 8; ++jj) {
        int srcl = (((quad * 2 + (jj >> 2)) & 3) << 4) + l16;
        float va = __shfl(pv[kh * 2][jj & 3], srcl);
        float vb = __shfl(pv[kh * 2 + 1][jj & 3], srcl);
        pb[jj] = (short)f2bf((quad >> 1) ? vb : va);
      }
#pragma unroll
      for (int i = 0; i < 8; ++i) {
        short8 vf = *(const short8*)(Vs + (i * 16 + l16) * 72 + kh * 32 + quad * 8);
        o[i] = __builtin_amdgcn_mfma_f32_16x16x32_bf16(vf, pb, o[i], 0, 0, 0);
      }
    }
  }
  float rinv = 1.f / l;
  size_t yrow = (size_t)(b * 2048 + q0 + l16) * 2048 + h * 128;
#pragma unroll
  for (int i = 0; i < 8; ++i)
#pragma unroll
    for (int r = 0; r < 4; ++r)
      Y[yrow + i * 16 + quad * 4 + r] = f2bf(o[i][r] * rinv);
}

extern "C" void kernel_launch(void* const* d_in, const int* in_sizes, int n_in,
                              void* d_out, int out_size, void* d_ws, size_t ws_size,
                              hipStream_t stream) {
  const float* x  = (const float*)d_in[0];   // [2,2048,2048] fp32
  const float* wq = (const float*)d_in[1];   // [2048,2048]
  const float* wk = (const float*)d_in[2];   // [2048,512]
  const float* wv = (const float*)d_in[3];   // [2048,512]
  const float* wo = (const float*)d_in[4];   // [2048,2048]
  float* outp = (float*)d_out;               // [2,2048,2048] fp32

  // d_out doubles as scratch before GEMM2 overwrites it entirely:
  unsigned short* WqkvT = (unsigned short*)d_out;            // [3072][2048] bf16
  unsigned short* VT    = WqkvT + (size_t)3072 * 2048;       // [2,4,128,2048] bf16
  // ws (42 MB): bf16 QKV | bf16 Yb; WoT overlays dead QKV after attention.
  unsigned short* QKV = (unsigned short*)d_ws;               // [4096][3072]
  unsigned short* Yb  = QKV + (size_t)4096 * 3072;           // [4096][2048]
  unsigned short* WoT = QKV;

  dim3 blk(256);
  k_transpose_f<<<dim3(32, 32), blk, 0, stream>>>(wq, WqkvT, 2048, 2048);
  k_transpose_f<<<dim3(8, 32), blk, 0, stream>>>(wk, WqkvT + (size_t)2048 * 2048, 2048, 512);
  k_transpose_f<<<dim3(8, 32), blk, 0, stream>>>(wv, WqkvT + (size_t)2560 * 2048, 2048, 512);

  k_gemm_f32A<<<dim3(24, 32), blk, 0, stream>>>(x, WqkvT, QKV, 4096, 3072, 2048);

  k_rope<<<dim3(20480), blk, 0, stream>>>(QKV);
  k_vtrans<<<dim3(8192), blk, 0, stream>>>(QKV, VT);

  k_attn<<<dim3(32, 32), blk, 0, stream>>>(QKV, VT, Yb);

  k_transpose_f<<<dim3(32, 32), blk, 0, stream>>>(wo, WoT, 2048, 2048);
  k_gemm_f32C<<<dim3(16, 32), blk, 0, stream>>>(Yb, WoT, outp, 4096, 2048, 2048);
}

// Round 9
// 378.629 us; speedup vs baseline: 1.3701x; 1.3701x over previous
//
#include <hip/hip_runtime.h>
#include <cstdint>
#include <cstddef>

typedef __attribute__((ext_vector_type(8))) short short8;
typedef __attribute__((ext_vector_type(4))) float f4;
typedef __attribute__((ext_vector_type(4))) unsigned int u4;

static __device__ __forceinline__ unsigned short f2bf(float x) {
  unsigned int u = __float_as_uint(x);
  unsigned int r = (u + 0x7FFFu + ((u >> 16) & 1u)) >> 16;  // RNE
  return (unsigned short)r;
}

// ---------------- transpose fp32 src -> bf16 dst: dst[n][k] = src[k][n] ----------------
__global__ __launch_bounds__(256) void k_transpose_f(
    const float* __restrict__ src, unsigned short* __restrict__ dst, int R, int C) {
  __shared__ alignas(16) unsigned short tile[64 * 72];
  int tid = threadIdx.x;
  int c0 = blockIdx.x * 64, r0 = blockIdx.y * 64;
#pragma unroll
  for (int s = 0; s < 2; ++s) {
    int chunk = tid + s * 256;
    int c8 = chunk & 7, r = chunk >> 3;
    const float* p = src + (size_t)(r0 + r) * C + c0 + c8 * 8;
    f4 a = *(const f4*)p;
    f4 b = *(const f4*)(p + 4);
    union { unsigned short u[8]; u4 v; } pk;
#pragma unroll
    for (int i = 0; i < 4; ++i) { pk.u[i] = f2bf(a[i]); pk.u[4 + i] = f2bf(b[i]); }
    *(u4*)(tile + r * 72 + c8 * 8) = pk.v;
  }
  __syncthreads();
#pragma unroll
  for (int s = 0; s < 2; ++s) {
    int chunk = tid + s * 256;
    int r8 = chunk & 7, c = chunk >> 3;
    union { unsigned short u[8]; u4 v; } pk;
#pragma unroll
    for (int i = 0; i < 8; ++i) pk.u[i] = tile[(r8 * 8 + i) * 72 + c];
    *(u4*)(dst + (size_t)(c0 + c) * R + r0 + r8 * 8) = pk.v;
  }
}

// ---------------- GEMM1: C_bf16[M,N] = A_f32[M,K] @ Bt_bf16[N,K]^T ----------------
__global__ __launch_bounds__(256) void k_gemm_f32A(
    const float* __restrict__ A, const unsigned short* __restrict__ Bt,
    unsigned short* __restrict__ C, int M, int N, int K) {
  __shared__ alignas(16) unsigned short As[128 * 72];
  __shared__ alignas(16) unsigned short Bs[128 * 72];
  int tid = threadIdx.x;
  int w = tid >> 6, lane = tid & 63, quad = lane >> 4, l16 = lane & 15;
  int wr = w >> 1, wc = w & 1;
  int bm = blockIdx.y * 128, bn = blockIdx.x * 128;
  f4 zero = {0.f, 0.f, 0.f, 0.f};
  f4 acc[4][4];
#pragma unroll
  for (int i = 0; i < 4; ++i)
#pragma unroll
    for (int j = 0; j < 4; ++j) acc[i][j] = zero;

  for (int k0 = 0; k0 < K; k0 += 64) {
    __syncthreads();
#pragma unroll
    for (int s = 0; s < 4; ++s) {
      int chunk = tid + s * 256;
      int c8 = chunk & 7, r = chunk >> 3;
      const float* p = A + (size_t)(bm + r) * K + k0 + c8 * 8;
      f4 a0 = *(const f4*)p;
      f4 a1 = *(const f4*)(p + 4);
      union { unsigned short u[8]; u4 v; } pk;
#pragma unroll
      for (int i = 0; i < 4; ++i) { pk.u[i] = f2bf(a0[i]); pk.u[4 + i] = f2bf(a1[i]); }
      *(u4*)(As + r * 72 + c8 * 8) = pk.v;
      *(u4*)(Bs + r * 72 + c8 * 8) =
          *(const u4*)(Bt + (size_t)(bn + r) * K + k0 + c8 * 8);
    }
    __syncthreads();
#pragma unroll
    for (int ks = 0; ks < 2; ++ks) {
      short8 af[4], bf[4];
#pragma unroll
      for (int i = 0; i < 4; ++i)
        af[i] = *(const short8*)(As + (wr * 64 + i * 16 + l16) * 72 + ks * 32 + quad * 8);
#pragma unroll
      for (int j = 0; j < 4; ++j)
        bf[j] = *(const short8*)(Bs + (wc * 64 + j * 16 + l16) * 72 + ks * 32 + quad * 8);
#pragma unroll
      for (int i = 0; i < 4; ++i)
#pragma unroll
        for (int j = 0; j < 4; ++j)
          acc[i][j] = __builtin_amdgcn_mfma_f32_16x16x32_bf16(af[i], bf[j], acc[i][j], 0, 0, 0);
    }
  }
#pragma unroll
  for (int i = 0; i < 4; ++i) {
    int row = bm + wr * 64 + i * 16 + quad * 4;
#pragma unroll
    for (int j = 0; j < 4; ++j) {
      int col = bn + wc * 64 + j * 16 + l16;
#pragma unroll
      for (int r = 0; r < 4; ++r)
        C[(size_t)(row + r) * N + col] = f2bf(acc[i][j][r]);
    }
  }
}

// ---------------- GEMM2: C_f32[M,N] = A_bf16[M,K] @ Bt_bf16[N,K]^T ----------------
__global__ __launch_bounds__(256) void k_gemm_f32C(
    const unsigned short* __restrict__ A, const unsigned short* __restrict__ Bt,
    float* __restrict__ C, int M, int N, int K) {
  __shared__ alignas(16) unsigned short As[128 * 72];
  __shared__ alignas(16) unsigned short Bs[128 * 72];
  int tid = threadIdx.x;
  int w = tid >> 6, lane = tid & 63, quad = lane >> 4, l16 = lane & 15;
  int wr = w >> 1, wc = w & 1;
  int bm = blockIdx.y * 128, bn = blockIdx.x * 128;
  f4 zero = {0.f, 0.f, 0.f, 0.f};
  f4 acc[4][4];
#pragma unroll
  for (int i = 0; i < 4; ++i)
#pragma unroll
    for (int j = 0; j < 4; ++j) acc[i][j] = zero;

  for (int k0 = 0; k0 < K; k0 += 64) {
    __syncthreads();
#pragma unroll
    for (int s = 0; s < 4; ++s) {
      int chunk = tid + s * 256;
      int c8 = chunk & 7, r = chunk >> 3;
      *(u4*)(As + r * 72 + c8 * 8) =
          *(const u4*)(A + (size_t)(bm + r) * K + k0 + c8 * 8);
      *(u4*)(Bs + r * 72 + c8 * 8) =
          *(const u4*)(Bt + (size_t)(bn + r) * K + k0 + c8 * 8);
    }
    __syncthreads();
#pragma unroll
    for (int ks = 0; ks < 2; ++ks) {
      short8 af[4], bf[4];
#pragma unroll
      for (int i = 0; i < 4; ++i)
        af[i] = *(const short8*)(As + (wr * 64 + i * 16 + l16) * 72 + ks * 32 + quad * 8);
#pragma unroll
      for (int j = 0; j < 4; ++j)
        bf[j] = *(const short8*)(Bs + (wc * 64 + j * 16 + l16) * 72 + ks * 32 + quad * 8);
#pragma unroll
      for (int i = 0; i < 4; ++i)
#pragma unroll
        for (int j = 0; j < 4; ++j)
          acc[i][j] = __builtin_amdgcn_mfma_f32_16x16x32_bf16(af[i], bf[j], acc[i][j], 0, 0, 0);
    }
  }
#pragma unroll
  for (int i = 0; i < 4; ++i) {
    int row = bm + wr * 64 + i * 16 + quad * 4;
#pragma unroll
    for (int j = 0; j < 4; ++j) {
      int col = bn + wc * 64 + j * 16 + l16;
#pragma unroll
      for (int r = 0; r < 4; ++r)
        C[(size_t)(row + r) * N + col] = acc[i][j][r];
    }
  }
}

// ---------------- RoPE in place on QKV (Q also scaled by 1/sqrt(D)) ----------------
__global__ __launch_bounds__(256) void k_rope(unsigned short* __restrict__ QKV) {
  int gid = blockIdx.x * 256 + threadIdx.x;
  const int TQ = 2 * 2048 * 16 * 64;
  bool isq = gid < TQ;
  int g = isq ? gid : gid - TQ;
  int d = g & 63; g >>= 6;
  int nh = isq ? 16 : 4;
  int h = g & (nh - 1); g >>= (isq ? 4 : 2);
  int t = g & 2047; int b = g >> 11;
  size_t p = (size_t)(b * 2048 + t) * 3072 + (isq ? 0 : 2048) + h * 128 + d;
  float x0 = __uint_as_float((unsigned int)QKV[p] << 16);
  float x1 = __uint_as_float((unsigned int)QKV[p + 64] << 16);
  float freq = exp2f(-(float)d * 0.20762050593046f);  // log2(10000)/64
  float ang = (float)t * freq;
  float cv = __cosf(ang), sv = __sinf(ang);
  float o0 = x0 * cv - x1 * sv;
  float o1 = x1 * cv + x0 * sv;
  if (isq) { o0 *= 0.088388347648318f; o1 *= 0.088388347648318f; }  // 1/sqrt(128)
  QKV[p] = f2bf(o0);
  QKV[p + 64] = f2bf(o1);
}

// ---------------- V transpose: VT[b,hk,d,t] = QKV[b*T+t, 2560+hk*128+d] ----------------
__global__ __launch_bounds__(256) void k_vtrans(
    const unsigned short* __restrict__ QKV, unsigned short* __restrict__ VT) {
  int gid = blockIdx.x * 256 + threadIdx.x;
  int t = gid & 2047; int g = gid >> 11;
  int d = g & 127; g >>= 7;
  int hk = g & 3; int b = g >> 2;
  VT[gid] = QKV[(size_t)(b * 2048 + t) * 3072 + 2560 + hk * 128 + d];
}

// ---------------- attention tile step: one 16q x 64k chunk for one wave ----------------
static __device__ __forceinline__ void attn_step(
    const unsigned short* __restrict__ Ks, const unsigned short* __restrict__ Vs,
    const short8* qf, f4* o, float& m, float& l,
    int quad, int l16, int qrow, int K0, bool mask) {
  f4 zero = {0.f, 0.f, 0.f, 0.f};
  f4 st[4];
#pragma unroll
  for (int kt = 0; kt < 4; ++kt) {
    st[kt] = zero;
#pragma unroll
    for (int ks = 0; ks < 4; ++ks) {
      short8 kf = *(const short8*)(Ks + (kt * 16 + l16) * 136 + ks * 32 + quad * 8);
      st[kt] = __builtin_amdgcn_mfma_f32_16x16x32_bf16(kf, qf[ks], st[kt], 0, 0, 0);
    }
  }
  if (mask) {
#pragma unroll
    for (int kt = 0; kt < 4; ++kt)
#pragma unroll
      for (int r = 0; r < 4; ++r)
        if (K0 + kt * 16 + quad * 4 + r > qrow) st[kt][r] = -1e30f;
  }
  float sm = -1e30f;
#pragma unroll
  for (int kt = 0; kt < 4; ++kt)
#pragma unroll
    for (int r = 0; r < 4; ++r) sm = fmaxf(sm, st[kt][r]);
  sm = fmaxf(sm, __shfl_xor(sm, 16));
  sm = fmaxf(sm, __shfl_xor(sm, 32));
  float mnew = fmaxf(m, sm);
  float alpha = __expf(m - mnew);
  f4 pv[4];
  float rs = 0.f;
#pragma unroll
  for (int kt = 0; kt < 4; ++kt)
#pragma unroll
    for (int r = 0; r < 4; ++r) {
      pv[kt][r] = __expf(st[kt][r] - mnew);
      rs += pv[kt][r];
    }
  rs += __shfl_xor(rs, 16);
  rs += __shfl_xor(rs, 32);
  l = l * alpha + rs;
  m = mnew;
#pragma unroll
  for (int i = 0; i < 8; ++i) o[i] *= alpha;
#pragma unroll
  for (int kh = 0; kh < 2; ++kh) {
    short8 pb;
#pragma unroll
    for (int j = 0; j < 8; ++j) {
      int srcl = (((quad * 2 + (j >> 2)) & 3) << 4) + l16;
      float va = __shfl(pv[kh * 2][j & 3], srcl);
      float vb = __shfl(pv[kh * 2 + 1][j & 3], srcl);
      pb[j] = (short)f2bf((quad >> 1) ? vb : va);
    }
#pragma unroll
    for (int i = 0; i < 8; ++i) {
      short8 vf = *(const short8*)(Vs + (i * 16 + l16) * 72 + kh * 32 + quad * 8);
      o[i] = __builtin_amdgcn_mfma_f32_16x16x32_bf16(vf, pb, o[i], 0, 0, 0);
    }
  }
}

// ---------------- Flash attention, paired q-tiles + double-buffered staging ----------------
// Block v in [0,16) handles q-tiles v and 31-v: uniform 33 tile-chunks/block.
// K/V for chunk kc+1 are global-loaded into registers BEFORE computing chunk kc,
// then written to the alternate LDS buffer after compute (vmcnt drain off the
// critical path). One barrier per iteration. Grid (16, 32) = 512 blocks, 2/CU.
__global__ __launch_bounds__(256, 2) void k_attn(
    const unsigned short* __restrict__ QKV,  // [B*T,3072], Q roped+scaled
    const unsigned short* __restrict__ VT,   // [B,4,128,T]
    unsigned short* __restrict__ Y) {        // [B*T,2048]
  __shared__ alignas(16) unsigned short Ks[2][64 * 136];   // 64 keys x 128 d
  __shared__ alignas(16) unsigned short Vs[2][128 * 72];   // 128 d x 64 keys
  int tid = threadIdx.x;
  int w = tid >> 6, lane = tid & 63, quad = lane >> 4, l16 = lane & 15;
  int bh = blockIdx.y; int b = bh >> 4, h = bh & 15, hk = h >> 2;
  int v = blockIdx.x;                 // 0..15
  int q0A = v * 64 + w * 16;          // early tile
  int q0B = (31 - v) * 64 + w * 16;   // late tile
  const unsigned short* Qh = QKV + (size_t)b * 2048 * 3072 + h * 128;
  const unsigned short* Kh = QKV + (size_t)b * 2048 * 3072 + 2048 + hk * 128;
  const unsigned short* Vh = VT + ((size_t)(b * 4 + hk) * 128) * 2048;

  // per-thread staging coordinates (s in 0..3):
  //   K: row rK = (tid>>4) + 16*s, col16 = tid&15
  //   V: row rV = (tid>>3) + 32*s, col8  = tid&7
  int rK0 = tid >> 4, cK = tid & 15;
  int rV0 = tid >> 3, cV = tid & 7;

  short8 qfA[4], qfB[4];
#pragma unroll
  for (int ks = 0; ks < 4; ++ks) {
    qfA[ks] = *(const short8*)(Qh + (size_t)(q0A + l16) * 3072 + ks * 32 + quad * 8);
    qfB[ks] = *(const short8*)(Qh + (size_t)(q0B + l16) * 3072 + ks * 32 + quad * 8);
  }

  f4 zero = {0.f, 0.f, 0.f, 0.f};
  f4 oA[8], oB[8];
#pragma unroll
  for (int i = 0; i < 8; ++i) { oA[i] = zero; oB[i] = zero; }
  float mA = -1e30f, lA = 0.f, mB = -1e30f, lB = 0.f;

  int nch = 32 - v;  // chunks 0..31-v (tile B's causal range)

  // prologue: stage chunk 0 into buffer 0
#pragma unroll
  for (int s = 0; s < 4; ++s) {
    int rK = rK0 + 16 * s;
    *(u4*)(&Ks[0][0] + rK * 136 + cK * 8) =
        *(const u4*)(Kh + (size_t)rK * 3072 + cK * 8);
    int rV = rV0 + 32 * s;
    *(u4*)(&Vs[0][0] + rV * 72 + cV * 8) =
        *(const u4*)(Vh + (size_t)rV * 2048 + cV * 8);
  }
  __syncthreads();

  for (int kc = 0; kc < nch; ++kc) {
    int cur = kc & 1, nxt = cur ^ 1;
    int K0 = kc * 64;
    bool have_next = (kc + 1) < nch;
    u4 kreg[4], vreg[4];
    if (have_next) {  // issue next-chunk loads before compute (latency overlap)
      int K0n = K0 + 64;
#pragma unroll
      for (int s = 0; s < 4; ++s) {
        int rK = rK0 + 16 * s;
        kreg[s] = *(const u4*)(Kh + (size_t)(K0n + rK) * 3072 + cK * 8);
        int rV = rV0 + 32 * s;
        vreg[s] = *(const u4*)(Vh + (size_t)rV * 2048 + K0n + cV * 8);
      }
    }

    if (kc <= v)  // block-uniform branch
      attn_step(&Ks[cur][0], &Vs[cur][0], qfA, oA, mA, lA, quad, l16, q0A + l16, K0, kc == v);
    attn_step(&Ks[cur][0], &Vs[cur][0], qfB, oB, mB, lB, quad, l16, q0B + l16, K0, kc == nch - 1);

    if (have_next) {  // vmcnt drain lands here, ~2000 cyc after issue
#pragma unroll
      for (int s = 0; s < 4; ++s) {
        int rK = rK0 + 16 * s;
        *(u4*)(&Ks[nxt][0] + rK * 136 + cK * 8) = kreg[s];
        int rV = rV0 + 32 * s;
        *(u4*)(&Vs[nxt][0] + rV * 72 + cV * 8) = vreg[s];
      }
    }
    __syncthreads();
  }

  float rA = 1.f / lA, rB = 1.f / lB;
  size_t yrowA = (size_t)(b * 2048 + q0A + l16) * 2048 + h * 128;
  size_t yrowB = (size_t)(b * 2048 + q0B + l16) * 2048 + h * 128;
#pragma unroll
  for (int i = 0; i < 8; ++i)
#pragma unroll
    for (int r = 0; r < 4; ++r) {
      Y[yrowA + i * 16 + quad * 4 + r] = f2bf(oA[i][r] * rA);
      Y[yrowB + i * 16 + quad * 4 + r] = f2bf(oB[i][r] * rB);
    }
}

extern "C" void kernel_launch(void* const* d_in, const int* in_sizes, int n_in,
                              void* d_out, int out_size, void* d_ws, size_t ws_size,
                              hipStream_t stream) {
  const float* x  = (const float*)d_in[0];   // [2,2048,2048] fp32
  const float* wq = (const float*)d_in[1];   // [2048,2048]
  const float* wk = (const float*)d_in[2];   // [2048,512]
  const float* wv = (const float*)d_in[3];   // [2048,512]
  const float* wo = (const float*)d_in[4];   // [2048,2048]
  float* outp = (float*)d_out;               // [2,2048,2048] fp32

  // d_out doubles as scratch before GEMM2 overwrites it entirely:
  unsigned short* WqkvT = (unsigned short*)d_out;            // [3072][2048] bf16
  unsigned short* VT    = WqkvT + (size_t)3072 * 2048;       // [2,4,128,2048] bf16
  // ws (42 MB): bf16 QKV | bf16 Yb; WoT overlays dead QKV after attention.
  unsigned short* QKV = (unsigned short*)d_ws;               // [4096][3072]
  unsigned short* Yb  = QKV + (size_t)4096 * 3072;           // [4096][2048]
  unsigned short* WoT = QKV;

  dim3 blk(256);
  k_transpose_f<<<dim3(32, 32), blk, 0, stream>>>(wq, WqkvT, 2048, 2048);
  k_transpose_f<<<dim3(8, 32), blk, 0, stream>>>(wk, WqkvT + (size_t)2048 * 2048, 2048, 512);
  k_transpose_f<<<dim3(8, 32), blk, 0, stream>>>(wv, WqkvT + (size_t)2560 * 2048, 2048, 512);

  k_gemm_f32A<<<dim3(24, 32), blk, 0, stream>>>(x, WqkvT, QKV, 4096, 3072, 2048);

  k_rope<<<dim3(20480), blk, 0, stream>>>(QKV);
  k_vtrans<<<dim3(8192), blk, 0, stream>>>(QKV, VT);

  k_attn<<<dim3(16, 32), blk, 0, stream>>>(QKV, VT, Yb);

  k_transpose_f<<<dim3(32, 32), blk, 0, stream>>>(wo, WoT, 2048, 2048);
  k_gemm_f32C<<<dim3(16, 32), blk, 0, stream>>>(Yb, WoT, outp, 4096, 2048, 2048);
}